// Round 1
// baseline (78.100 us; speedup 1.0000x reference)
//
#include <hip/hip_runtime.h>

#define NA 96
#define NB 96
#define NS 64

// One block per query. Each block:
//  - soft: iterate K^3 neighbors of clip(rint(q),1,N-2), accumulate softmax
//    numerator/denominator (no max-subtraction needed: args <= 0, min dist <= 3
//    so largest exp term >= e^-30, well inside f32 range).
//  - hard: nearest lattice point = per-coordinate round (ties -> floor, matching
//    argmin-first-index semantics), single gather.
__global__ __launch_bounds__(256) void latent_lookup_kernel(
    const float* __restrict__ q,        // [B,3]
    const float* __restrict__ rel,      // [NA*NB*NS]
    const float* __restrict__ origin,   // [3]
    const float* __restrict__ spacing,  // [3]
    const float* __restrict__ temp,     // [1]
    const int*   __restrict__ ksize,    // [1]
    float* __restrict__ out,            // [2,B]
    int B)
{
    const int b   = blockIdx.x;
    const int tid = threadIdx.x;

    const float qx = q[b * 3 + 0];
    const float qy = q[b * 3 + 1];
    const float qz = q[b * 3 + 2];

    const float inv_t = 1.0f / (temp[0] + 1e-8f);

    const int ks     = ksize[0];
    const int radius = ks >> 1;
    const int K      = 2 * radius + 1;
    const int K3     = K * K * K;
    const int K2     = K * K;

    // rel_pos = (q - origin) / spacing ; voxel = clip(rint(rel_pos), 1, N-2)
    const float rx = (qx - origin[0]) / spacing[0];
    const float ry = (qy - origin[1]) / spacing[1];
    const float rz = (qz - origin[2]) / spacing[2];
    int vx = (int)rintf(rx); vx = min(max(vx, 1), NA - 2);
    int vy = (int)rintf(ry); vy = min(max(vy, 1), NB - 2);
    int vz = (int)rintf(rz); vz = min(max(vz, 1), NS - 2);

    float sw  = 0.0f;   // sum of weights
    float swm = 0.0f;   // sum of weight * metric

    for (int k = tid; k < K3; k += blockDim.x) {
        int ox  = k / K2;
        int rem = k - ox * K2;
        int oy  = rem / K;
        int oz  = rem - oy * K;

        int cx = vx + ox - radius; cx = min(max(cx, 0), NA - 1);
        int cy = vy + oy - radius; cy = min(max(cy, 0), NB - 1);
        int cz = vz + oz - radius; cz = min(max(cz, 0), NS - 1);

        // neighbor_xyz == (cx,cy,cz) since indices_3d is the unit meshgrid
        float dx = qx - (float)cx;
        float dy = qy - (float)cy;
        float dz = qz - (float)cz;
        float d  = dx * dx + dy * dy + dz * dz;

        float w = __expf(-d * inv_t);
        float m = rel[(cx * NB + cy) * NS + cz];
        sw  += w;
        swm += w * m;
    }

    // block reduction: wave64 shuffle, then LDS across waves
    __shared__ float red[4][2];
    const int wave = tid >> 6;
    const int lane = tid & 63;
    #pragma unroll
    for (int off = 32; off > 0; off >>= 1) {
        sw  += __shfl_down(sw,  off);
        swm += __shfl_down(swm, off);
    }
    if (lane == 0) {
        red[wave][0] = sw;
        red[wave][1] = swm;
    }
    __syncthreads();

    if (tid == 0) {
        float tsw = 0.0f, tswm = 0.0f;
        #pragma unroll
        for (int w = 0; w < 4; ++w) {
            tsw  += red[w][0];
            tswm += red[w][1];
        }

        // hard: nearest integer lattice point; ties (frac == 0.5) -> floor,
        // matching argmin's first-minimum (lower flat index) semantics.
        float fx = floorf(qx); int hx = (int)fx + ((qx - fx) > 0.5f ? 1 : 0);
        float fy = floorf(qy); int hy = (int)fy + ((qy - fy) > 0.5f ? 1 : 0);
        float fz = floorf(qz); int hz = (int)fz + ((qz - fz) > 0.5f ? 1 : 0);
        hx = min(max(hx, 0), NA - 1);
        hy = min(max(hy, 0), NB - 1);
        hz = min(max(hz, 0), NS - 1);

        out[b]     = rel[(hx * NB + hy) * NS + hz];   // hard
        out[B + b] = tswm / tsw;                      // soft
    }
}

extern "C" void kernel_launch(void* const* d_in, const int* in_sizes, int n_in,
                              void* d_out, int out_size, void* d_ws, size_t ws_size,
                              hipStream_t stream) {
    const float* q       = (const float*)d_in[0];  // [B,3]
    // d_in[1] = indices_3d — unit meshgrid, values synthesized arithmetically
    const float* rel     = (const float*)d_in[2];  // [NA,NB,NS]
    const float* origin  = (const float*)d_in[3];  // [3]
    const float* spacing = (const float*)d_in[4];  // [3]
    const float* temp    = (const float*)d_in[5];  // [1]
    const int*   ksize   = (const int*)d_in[6];    // [1]
    float* out = (float*)d_out;

    const int B = in_sizes[0] / 3;

    latent_lookup_kernel<<<B, 256, 0, stream>>>(q, rel, origin, spacing, temp,
                                                ksize, out, B);
}

// Round 2
// 74.315 us; speedup vs baseline: 1.0509x; 1.0509x over previous
//
#include <hip/hip_runtime.h>

#define NA 96
#define NB 96
#define NS 64

// ---------------------------------------------------------------------------
// soft-path accumulator, compile-time kernel size K (K=15 is the shipped case).
// Each of the 256 threads handles ceil(K^3/256) neighbors, fully unrolled so
// all gather loads are in flight together (ILP-latency hiding; table is
// L2-resident so each load is ~200cy — overlapping them is the whole game).
// ---------------------------------------------------------------------------
template <int K>
__device__ __forceinline__ void soft_accum_tpl(
    int tid, int vx, int vy, int vz,
    float qx, float qy, float qz, float inv_t,
    const float* __restrict__ rel,
    float& sw, float& swm)
{
    constexpr int K2 = K * K;
    constexpr int K3 = K * K * K;
    constexpr int R  = K / 2;
    constexpr int ITER = (K3 + 255) / 256;

    #pragma unroll
    for (int i = 0; i < ITER; ++i) {
        int k = tid + i * 256;
        bool valid = (k < K3);
        int kk = valid ? k : 0;
        // constant divisors -> magic-multiply, no div emulation
        int ox  = kk / K2;
        int rem = kk - ox * K2;
        int oy  = rem / K;
        int oz  = rem - oy * K;

        int cx = vx + ox - R; cx = min(max(cx, 0), NA - 1);
        int cy = vy + oy - R; cy = min(max(cy, 0), NB - 1);
        int cz = vz + oz - R; cz = min(max(cz, 0), NS - 1);

        float dx = qx - (float)cx;
        float dy = qy - (float)cy;
        float dz = qz - (float)cz;
        float d  = dx * dx + dy * dy + dz * dz;

        float m = rel[(cx * NB + cy) * NS + cz];
        float w = valid ? __expf(-d * inv_t) : 0.0f;
        sw  += w;
        swm += w * m;
    }
}

// generic fallback (runtime K) — correctness safety net only
__device__ __noinline__ void soft_accum_generic(
    int tid, int vx, int vy, int vz, int K,
    float qx, float qy, float qz, float inv_t,
    const float* __restrict__ rel,
    float& sw, float& swm)
{
    const int K2 = K * K;
    const int K3 = K2 * K;
    const int R  = K / 2;
    for (int k = tid; k < K3; k += 256) {
        int ox  = k / K2;
        int rem = k - ox * K2;
        int oy  = rem / K;
        int oz  = rem - oy * K;
        int cx = vx + ox - R; cx = min(max(cx, 0), NA - 1);
        int cy = vy + oy - R; cy = min(max(cy, 0), NB - 1);
        int cz = vz + oz - R; cz = min(max(cz, 0), NS - 1);
        float dx = qx - (float)cx;
        float dy = qy - (float)cy;
        float dz = qz - (float)cz;
        float d  = dx * dx + dy * dy + dz * dz;
        float w = __expf(-d * inv_t);
        sw  += w;
        swm += w * rel[(cx * NB + cy) * NS + cz];
    }
}

__global__ __launch_bounds__(256) void latent_lookup_kernel(
    const float* __restrict__ q,        // [B,3]
    const float* __restrict__ rel,      // [NA*NB*NS]
    const float* __restrict__ origin,   // [3]
    const float* __restrict__ spacing,  // [3]
    const float* __restrict__ temp,     // [1]
    const int*   __restrict__ ksize,    // [1]
    float* __restrict__ out,            // [2,B]
    int B)
{
    const int b   = blockIdx.x;
    const int tid = threadIdx.x;

    const float qx = q[b * 3 + 0];
    const float qy = q[b * 3 + 1];
    const float qz = q[b * 3 + 2];

    const float inv_t = 1.0f / (temp[0] + 1e-8f);
    const int   ks    = ksize[0];

    // voxel = clip(rint((q - origin)/spacing), 1, N-2)
    const float rx = (qx - origin[0]) / spacing[0];
    const float ry = (qy - origin[1]) / spacing[1];
    const float rz = (qz - origin[2]) / spacing[2];
    int vx = (int)rintf(rx); vx = min(max(vx, 1), NA - 2);
    int vy = (int)rintf(ry); vy = min(max(vy, 1), NB - 2);
    int vz = (int)rintf(rz); vz = min(max(vz, 1), NS - 2);

    float sw  = 0.0f;
    float swm = 0.0f;

    if (ks == 15) {   // uniform branch; shipped configuration
        soft_accum_tpl<15>(tid, vx, vy, vz, qx, qy, qz, inv_t, rel, sw, swm);
    } else {
        soft_accum_generic(tid, vx, vy, vz, ks, qx, qy, qz, inv_t, rel, sw, swm);
    }

    // block reduction: wave64 shuffle, then LDS across waves
    __shared__ float red[4][2];
    const int wave = tid >> 6;
    const int lane = tid & 63;
    #pragma unroll
    for (int off = 32; off > 0; off >>= 1) {
        sw  += __shfl_down(sw,  off);
        swm += __shfl_down(swm, off);
    }
    if (lane == 0) {
        red[wave][0] = sw;
        red[wave][1] = swm;
    }
    __syncthreads();

    if (tid == 0) {
        float tsw = 0.0f, tswm = 0.0f;
        #pragma unroll
        for (int w = 0; w < 4; ++w) {
            tsw  += red[w][0];
            tswm += red[w][1];
        }

        // hard: nearest lattice point; ties (frac==0.5) -> floor, matching
        // argmin first-minimum (lower flat index) semantics.
        float fx = floorf(qx); int hx = (int)fx + ((qx - fx) > 0.5f ? 1 : 0);
        float fy = floorf(qy); int hy = (int)fy + ((qy - fy) > 0.5f ? 1 : 0);
        float fz = floorf(qz); int hz = (int)fz + ((qz - fz) > 0.5f ? 1 : 0);
        hx = min(max(hx, 0), NA - 1);
        hy = min(max(hy, 0), NB - 1);
        hz = min(max(hz, 0), NS - 1);

        out[b]     = rel[(hx * NB + hy) * NS + hz];   // hard
        out[B + b] = tswm / tsw;                      // soft
    }
}

extern "C" void kernel_launch(void* const* d_in, const int* in_sizes, int n_in,
                              void* d_out, int out_size, void* d_ws, size_t ws_size,
                              hipStream_t stream) {
    const float* q       = (const float*)d_in[0];  // [B,3]
    // d_in[1] = indices_3d — unit meshgrid, synthesized arithmetically
    const float* rel     = (const float*)d_in[2];  // [NA,NB,NS]
    const float* origin  = (const float*)d_in[3];  // [3]
    const float* spacing = (const float*)d_in[4];  // [3]
    const float* temp    = (const float*)d_in[5];  // [1]
    const int*   ksize   = (const int*)d_in[6];    // [1]
    float* out = (float*)d_out;

    const int B = in_sizes[0] / 3;

    latent_lookup_kernel<<<B, 256, 0, stream>>>(q, rel, origin, spacing, temp,
                                                ksize, out, B);
}